// Round 1
// 304.704 us; speedup vs baseline: 1.0333x; 1.0333x over previous
//
#include <hip/hip_runtime.h>
#include <math.h>

// Problem constants: B=4096, T=200, D=64
#define TT 200
#define MTS 72   // Mt row stride in bf16 elems (144 B rows: 16B-aligned)

typedef __attribute__((ext_vector_type(8))) short bf16x8;  // 8 bf16 = 4 VGPRs
typedef __attribute__((ext_vector_type(4))) float f32x4;

__device__ __forceinline__ float sigmoidf_(float x) {
    return 1.0f / (1.0f + __expf(-x));
}
// bf16 RNE convert via bit ops
__device__ __forceinline__ short f2bf(float x) {
    unsigned u = __float_as_uint(x);
    u += 0x7fff + ((u >> 16) & 1);
    return (short)(u >> 16);
}
__device__ __forceinline__ float bf2f(short s) {
    return __uint_as_float(((unsigned)(unsigned short)s) << 16);
}
__device__ __forceinline__ void build_hi(float4 v0, float4 v1, bf16x8& hi) {
    float xs[8] = {v0.x, v0.y, v0.z, v0.w, v1.x, v1.y, v1.z, v1.w};
    #pragma unroll
    for (int j = 0; j < 8; j++) hi[j] = f2bf(xs[j]);
}

// One wave = one batch row. 4 rows per 256-thread block. Single pass over keys
// (online softmax), tile count trimmed to ceil(len/16). No barriers after the
// initial W2 staging barrier.
__global__ __launch_bounds__(256) void din_attn_flash(
    const float* __restrict__ queries,     // [B,64]
    const float* __restrict__ keys,        // [B,200,64]
    const int*   __restrict__ keys_length, // [B]
    const float* __restrict__ W1,          // [256,16]
    const float* __restrict__ b1,          // [16]
    const float* __restrict__ W2,          // [16,8]
    const float* __restrict__ b2,          // [8]
    const float* __restrict__ W3,          // [8,1]
    const float* __restrict__ b3,          // [1]
    const float* __restrict__ W4,          // [64,64]
    const float* __restrict__ b4,          // [64]
    float* __restrict__ out,               // [B,64]
    int Bn)
{
    __shared__ __align__(16) short MtHi[4][16 * MTS];   // per-wave folded W1^T hi
    __shared__ __align__(16) short MtLo[4][16 * MTS];   // per-wave folded W1^T lo
    __shared__ __align__(16) float w2s[16 * 8];         // staged W2 (block-shared)
    __shared__ __align__(16) float vS[4][64];           // per-wave attn-weighted key sum

    const int tid  = threadIdx.x;
    const int w    = tid >> 6;
    const int lane = tid & 63;
    const int m16  = lane & 15;
    const int quad = lane >> 4;

    // ---- stage W2 once; the ONLY block barrier ----
    if (tid < 128) w2s[tid] = W2[tid];
    __syncthreads();

    const int b = blockIdx.x * 4 + w;
    if (b >= Bn) return;
    const int len = __builtin_amdgcn_readfirstlane(keys_length[b]);
    const float* kb = keys + (size_t)b * (TT * 64);

    // ---- fold W1 per wave: lane = (d2 = lane>>2 in 0..15, hg = lane&3) ----
    float cp0 = 0.f, cp1 = 0.f, cp2 = 0.f, cp3 = 0.f;
    {
        const int d2 = lane >> 2;
        const int hg = lane & 3;
        const float4* W1v = (const float4*)W1;   // [256][4] of float4
        #pragma unroll
        for (int dg = 0; dg < 4; dg++) {
            const int d = dg * 16 + d2;
            const float q = queries[b * 64 + d];
            float4 a  = W1v[(0   + d) * 4 + hg];
            float4 bb = W1v[(64  + d) * 4 + hg];
            float4 cc = W1v[(128 + d) * 4 + hg];
            float4 dd = W1v[(192 + d) * 4 + hg];
            float mv0 = bb.x - cc.x + q * dd.x;
            float mv1 = bb.y - cc.y + q * dd.y;
            float mv2 = bb.z - cc.z + q * dd.z;
            float mv3 = bb.w - cc.w + q * dd.w;
            cp0 += q * (a.x + cc.x);
            cp1 += q * (a.y + cc.y);
            cp2 += q * (a.z + cc.z);
            cp3 += q * (a.w + cc.w);
            const int hb = hg * 4;
            short h0 = f2bf(mv0), h1 = f2bf(mv1), h2 = f2bf(mv2), h3 = f2bf(mv3);
            MtHi[w][(hb + 0) * MTS + d] = h0;
            MtHi[w][(hb + 1) * MTS + d] = h1;
            MtHi[w][(hb + 2) * MTS + d] = h2;
            MtHi[w][(hb + 3) * MTS + d] = h3;
            MtLo[w][(hb + 0) * MTS + d] = f2bf(mv0 - bf2f(h0));
            MtLo[w][(hb + 1) * MTS + d] = f2bf(mv1 - bf2f(h1));
            MtLo[w][(hb + 2) * MTS + d] = f2bf(mv2 - bf2f(h2));
            MtLo[w][(hb + 3) * MTS + d] = f2bf(mv3 - bf2f(h3));
        }
        // reduce cp over d2 (lane bits 2..5) -> every lane holds totals for its hg
        #pragma unroll
        for (int mask = 4; mask <= 32; mask <<= 1) {
            cp0 += __shfl_xor(cp0, mask, 64);
            cp1 += __shfl_xor(cp1, mask, 64);
            cp2 += __shfl_xor(cp2, mask, 64);
            cp3 += __shfl_xor(cp3, mask, 64);
        }
    }
    // pull cvec for h = quad*4 + r from lane 'quad' (which holds hg == quad)
    float cv4[4];
    cv4[0] = __shfl(cp0, quad, 64) + b1[quad * 4 + 0];
    cv4[1] = __shfl(cp1, quad, 64) + b1[quad * 4 + 1];
    cv4[2] = __shfl(cp2, quad, 64) + b1[quad * 4 + 2];
    cv4[3] = __shfl(cp3, quad, 64) + b1[quad * 4 + 3];

    // same-wave LDS write -> read: compiler fence (HW DS ops are in-order per wave)
    asm volatile("" ::: "memory");
    __builtin_amdgcn_wave_barrier();

    // ---- A-operand frags (Mt): A[row=h=m16][k=d=quad*8+j] ----
    const int bb0 = m16 * MTS + quad * 8;
    const bf16x8 Bh0 = *(const bf16x8*)&MtHi[w][bb0];
    const bf16x8 Bh1 = *(const bf16x8*)&MtHi[w][bb0 + 32];
    const bf16x8 Bl0 = *(const bf16x8*)&MtLo[w][bb0];
    const bf16x8 Bl1 = *(const bf16x8*)&MtLo[w][bb0 + 32];

    const float4* w2s4 = (const float4*)w2s;
    const float4 b2a = *(const float4*)(b2);
    const float4 b2b = *(const float4*)(b2 + 4);
    const float4 w3a = *(const float4*)(W3);
    const float4 w3b = *(const float4*)(W3 + 4);
    const float  b3v = b3[0];

    // ---- online-softmax flash loop over trimmed tiles ----
    float mrun = -3.0e38f;
    float ssum = 0.0f;
    float o[16];
    #pragma unroll
    for (int j = 0; j < 16; j++) o[j] = 0.0f;

    const int ntiles = (len == 0) ? 13 : ((len + 15) >> 4);

    // prefetch tile 0: lane holds keys[t = m16][quad*8 .. +7] and [+32 .. +39]
    const float* kp0 = kb + m16 * 64 + quad * 8;
    float4 c0 = *(const float4*)(kp0);
    float4 c1 = *(const float4*)(kp0 + 4);
    float4 c2 = *(const float4*)(kp0 + 32);
    float4 c3 = *(const float4*)(kp0 + 36);

    for (int tile = 0; tile < ntiles; tile++) {
        float4 n0, n1, n2, n3;
        const bool pf = (tile + 1 < ntiles);
        if (pf) {
            int tr = (tile + 1) * 16 + m16;
            if (tr > TT - 1) tr = TT - 1;
            const float* np = kb + tr * 64 + quad * 8;
            n0 = *(const float4*)(np);
            n1 = *(const float4*)(np + 4);
            n2 = *(const float4*)(np + 32);
            n3 = *(const float4*)(np + 36);
        }
        bf16x8 ah0, ah1;
        build_hi(c0, c1, ah0);
        build_hi(c2, c3, ah1);
        // swapped operands: D[h][t] -> lane holds t=m16, h=quad*4+r
        f32x4 acc = {0.f, 0.f, 0.f, 0.f};
        acc = __builtin_amdgcn_mfma_f32_16x16x32_bf16(Bh0, ah0, acc, 0, 0, 0);
        acc = __builtin_amdgcn_mfma_f32_16x16x32_bf16(Bl0, ah0, acc, 0, 0, 0);
        acc = __builtin_amdgcn_mfma_f32_16x16x32_bf16(Bh1, ah1, acc, 0, 0, 0);
        acc = __builtin_amdgcn_mfma_f32_16x16x32_bf16(Bl1, ah1, acc, 0, 0, 0);

        // layer 2 partial over this lane's 4 h's (h1 kept f32 now)
        float s2[8] = {b2a.x, b2a.y, b2a.z, b2a.w, b2b.x, b2b.y, b2b.z, b2b.w};
        #pragma unroll
        for (int r = 0; r < 4; r++) {
            const float h1 = sigmoidf_(acc[r] + cv4[r]);
            const float4 wa = w2s4[(quad * 4 + r) * 2];
            const float4 wb = w2s4[(quad * 4 + r) * 2 + 1];
            s2[0] = fmaf(h1, wa.x, s2[0]);
            s2[1] = fmaf(h1, wa.y, s2[1]);
            s2[2] = fmaf(h1, wa.z, s2[2]);
            s2[3] = fmaf(h1, wa.w, s2[3]);
            s2[4] = fmaf(h1, wb.x, s2[4]);
            s2[5] = fmaf(h1, wb.y, s2[5]);
            s2[6] = fmaf(h1, wb.z, s2[6]);
            s2[7] = fmaf(h1, wb.w, s2[7]);
        }
        // reduce s2 across quads (same t) -> all lanes hold full s2
        #pragma unroll
        for (int j = 0; j < 8; j++) {
            s2[j] += __shfl_xor(s2[j], 16, 64);
            s2[j] += __shfl_xor(s2[j], 32, 64);
        }
        float s3 = b3v;
        s3 = fmaf(sigmoidf_(s2[0]), w3a.x, s3);
        s3 = fmaf(sigmoidf_(s2[1]), w3a.y, s3);
        s3 = fmaf(sigmoidf_(s2[2]), w3a.z, s3);
        s3 = fmaf(sigmoidf_(s2[3]), w3a.w, s3);
        s3 = fmaf(sigmoidf_(s2[4]), w3b.x, s3);
        s3 = fmaf(sigmoidf_(s2[5]), w3b.y, s3);
        s3 = fmaf(sigmoidf_(s2[6]), w3b.z, s3);
        s3 = fmaf(sigmoidf_(s2[7]), w3b.w, s3);

        const int tg = tile * 16 + m16;
        float sc = s3 * 0.125f;                     // / sqrt(64)
        if (tg >= len) sc = -536870912.0f;          // f32(NEG_INF) * 0.125
        if (tg >= TT)  sc = -INFINITY;              // clamped duplicate rows -> p = 0

        // tile max over 16 t (lanes differ only in m16; identical across quads)
        float mx = sc;
        mx = fmaxf(mx, __shfl_xor(mx, 1, 64));
        mx = fmaxf(mx, __shfl_xor(mx, 2, 64));
        mx = fmaxf(mx, __shfl_xor(mx, 4, 64));
        mx = fmaxf(mx, __shfl_xor(mx, 8, 64));
        const float mnew = fmaxf(mrun, mx);
        const float fr = __expf(mrun - mnew);       // rescale (==1 when no new max)
        const float p  = __expf(sc - mnew);         // masked lanes underflow to 0 exactly
        mrun = mnew;
        float ps = p;
        ps += __shfl_xor(ps, 1, 64);
        ps += __shfl_xor(ps, 2, 64);
        ps += __shfl_xor(ps, 4, 64);
        ps += __shfl_xor(ps, 8, 64);
        ssum = fmaf(ssum, fr, ps);
        // per-lane o covers t == m16 series; cross-t reduce deferred to the end
        o[0]  = fmaf(o[0],  fr, p * c0.x);
        o[1]  = fmaf(o[1],  fr, p * c0.y);
        o[2]  = fmaf(o[2],  fr, p * c0.z);
        o[3]  = fmaf(o[3],  fr, p * c0.w);
        o[4]  = fmaf(o[4],  fr, p * c1.x);
        o[5]  = fmaf(o[5],  fr, p * c1.y);
        o[6]  = fmaf(o[6],  fr, p * c1.z);
        o[7]  = fmaf(o[7],  fr, p * c1.w);
        o[8]  = fmaf(o[8],  fr, p * c2.x);
        o[9]  = fmaf(o[9],  fr, p * c2.y);
        o[10] = fmaf(o[10], fr, p * c2.z);
        o[11] = fmaf(o[11], fr, p * c2.w);
        o[12] = fmaf(o[12], fr, p * c3.x);
        o[13] = fmaf(o[13], fr, p * c3.y);
        o[14] = fmaf(o[14], fr, p * c3.z);
        o[15] = fmaf(o[15], fr, p * c3.w);

        if (pf) { c0 = n0; c1 = n1; c2 = n2; c3 = n3; }
    }

    // ---- final cross-t reduction (over m16 lanes) ----
    #pragma unroll
    for (int mask = 1; mask <= 8; mask <<= 1) {
        #pragma unroll
        for (int j = 0; j < 16; j++) o[j] += __shfl_xor(o[j], mask, 64);
    }
    const float inv = 1.0f / ssum;   // ssum >= 1 always (len==0 -> 200)
    if (m16 == 0) {
        #pragma unroll
        for (int j = 0; j < 8; j++) vS[w][quad * 8 + j]      = o[j] * inv;
        #pragma unroll
        for (int j = 0; j < 8; j++) vS[w][32 + quad * 8 + j] = o[8 + j] * inv;
    }
    asm volatile("" ::: "memory");
    __builtin_amdgcn_wave_barrier();

    // ---- out[i=lane] = b4[i] + sum_d v[d] * W4[d][i] (W4 is L2-hot) ----
    float po = b4[lane];
    const float4* vS4 = (const float4*)&vS[w][0];
    #pragma unroll 4
    for (int d0 = 0; d0 < 16; d0++) {
        const float4 vv = vS4[d0];
        const float* w4p = W4 + d0 * 256 + lane;
        po = fmaf(vv.x, w4p[0],   po);
        po = fmaf(vv.y, w4p[64],  po);
        po = fmaf(vv.z, w4p[128], po);
        po = fmaf(vv.w, w4p[192], po);
    }
    out[(size_t)b * 64 + lane] = po;
}

extern "C" void kernel_launch(void* const* d_in, const int* in_sizes, int n_in,
                              void* d_out, int out_size, void* d_ws, size_t ws_size,
                              hipStream_t stream) {
    const float* queries     = (const float*)d_in[0];
    const float* keys        = (const float*)d_in[1];
    const int*   keys_length = (const int*)  d_in[2];
    const float* W1 = (const float*)d_in[3];
    const float* b1 = (const float*)d_in[4];
    const float* W2 = (const float*)d_in[5];
    const float* b2 = (const float*)d_in[6];
    const float* W3 = (const float*)d_in[7];
    const float* b3 = (const float*)d_in[8];
    const float* W4 = (const float*)d_in[9];
    const float* b4 = (const float*)d_in[10];
    float* out = (float*)d_out;

    const int Bn = in_sizes[2];   // 4096
    const int blocks = (Bn + 3) >> 2;   // 4 rows per block (1 wave each)
    din_attn_flash<<<blocks, 256, 0, stream>>>(
        queries, keys, keys_length, W1, b1, W2, b2, W3, b3, W4, b4, out, Bn);
}

// Round 2
// 294.490 us; speedup vs baseline: 1.0691x; 1.0347x over previous
//
#include <hip/hip_runtime.h>
#include <math.h>

// Problem constants: B=4096, T=200, D=64
#define TT 200
#define MTS 72   // Mt row stride in bf16 elems (144 B rows: 16B-aligned)

typedef __attribute__((ext_vector_type(8))) short bf16x8;  // 8 bf16 = 4 VGPRs
typedef __attribute__((ext_vector_type(4))) float f32x4;

__device__ __forceinline__ float sigmoidf_(float x) {
    return 1.0f / (1.0f + __expf(-x));
}
// bf16 RNE convert via bit ops
__device__ __forceinline__ short f2bf(float x) {
    unsigned u = __float_as_uint(x);
    u += 0x7fff + ((u >> 16) & 1);
    return (short)(u >> 16);
}
__device__ __forceinline__ float bf2f(short s) {
    return __uint_as_float(((unsigned)(unsigned short)s) << 16);
}
__device__ __forceinline__ void build_hi(float4 v0, float4 v1, bf16x8& hi) {
    float xs[8] = {v0.x, v0.y, v0.z, v0.w, v1.x, v1.y, v1.z, v1.w};
    #pragma unroll
    for (int j = 0; j < 8; j++) hi[j] = f2bf(xs[j]);
}

// One wave = one batch row; 4 waves (rows) per 256-thread block.
// Single pass over keys, tiles trimmed to ceil(len/16).
// Fixed-bound softmax (M from |b3|+sum|W3|): no online max/rescale chain.
// ZERO block barriers.
__global__ __launch_bounds__(256) void din_attn_flash(
    const float* __restrict__ queries,     // [B,64]
    const float* __restrict__ keys,        // [B,200,64]
    const int*   __restrict__ keys_length, // [B]
    const float* __restrict__ W1,          // [256,16]
    const float* __restrict__ b1,          // [16]
    const float* __restrict__ W2,          // [16,8]
    const float* __restrict__ b2,          // [8]
    const float* __restrict__ W3,          // [8,1]
    const float* __restrict__ b3,          // [1]
    const float* __restrict__ W4,          // [64,64]
    const float* __restrict__ b4,          // [64]
    float* __restrict__ out,               // [B,64]
    int Bn)
{
    __shared__ __align__(16) short MtHi[4][16 * MTS];   // per-wave folded W1^T hi
    __shared__ __align__(16) short MtLo[4][16 * MTS];   // per-wave folded W1^T lo
    __shared__ __align__(16) float vS[4][64];           // per-wave attn-weighted key sum

    const int tid  = threadIdx.x;
    const int w    = tid >> 6;
    const int lane = tid & 63;
    const int m16  = lane & 15;
    const int quad = lane >> 4;

    const int b = blockIdx.x * 4 + w;
    if (b >= Bn) return;
    const int len = __builtin_amdgcn_readfirstlane(keys_length[b]);
    const float* kb = keys + (size_t)b * (TT * 64);

    // ---- fold W1 per wave: lane = (d2 = lane>>2 in 0..15, hg = lane&3) ----
    float cp0 = 0.f, cp1 = 0.f, cp2 = 0.f, cp3 = 0.f;
    {
        const int d2 = lane >> 2;
        const int hg = lane & 3;
        const float4* W1v = (const float4*)W1;   // [256][4] of float4
        #pragma unroll
        for (int dg = 0; dg < 4; dg++) {
            const int d = dg * 16 + d2;
            const float q = queries[b * 64 + d];
            float4 a  = W1v[(0   + d) * 4 + hg];
            float4 bb = W1v[(64  + d) * 4 + hg];
            float4 cc = W1v[(128 + d) * 4 + hg];
            float4 dd = W1v[(192 + d) * 4 + hg];
            float mv0 = bb.x - cc.x + q * dd.x;
            float mv1 = bb.y - cc.y + q * dd.y;
            float mv2 = bb.z - cc.z + q * dd.z;
            float mv3 = bb.w - cc.w + q * dd.w;
            cp0 += q * (a.x + cc.x);
            cp1 += q * (a.y + cc.y);
            cp2 += q * (a.z + cc.z);
            cp3 += q * (a.w + cc.w);
            const int hb = hg * 4;
            short h0 = f2bf(mv0), h1 = f2bf(mv1), h2 = f2bf(mv2), h3 = f2bf(mv3);
            MtHi[w][(hb + 0) * MTS + d] = h0;
            MtHi[w][(hb + 1) * MTS + d] = h1;
            MtHi[w][(hb + 2) * MTS + d] = h2;
            MtHi[w][(hb + 3) * MTS + d] = h3;
            MtLo[w][(hb + 0) * MTS + d] = f2bf(mv0 - bf2f(h0));
            MtLo[w][(hb + 1) * MTS + d] = f2bf(mv1 - bf2f(h1));
            MtLo[w][(hb + 2) * MTS + d] = f2bf(mv2 - bf2f(h2));
            MtLo[w][(hb + 3) * MTS + d] = f2bf(mv3 - bf2f(h3));
        }
        // reduce cp over d2 (lane bits 2..5) -> every lane holds totals for its hg
        #pragma unroll
        for (int mask = 4; mask <= 32; mask <<= 1) {
            cp0 += __shfl_xor(cp0, mask, 64);
            cp1 += __shfl_xor(cp1, mask, 64);
            cp2 += __shfl_xor(cp2, mask, 64);
            cp3 += __shfl_xor(cp3, mask, 64);
        }
    }
    // pull cvec for h = quad*4 + r from lane 'quad' (which holds hg == quad)
    float cv4[4];
    cv4[0] = __shfl(cp0, quad, 64) + b1[quad * 4 + 0];
    cv4[1] = __shfl(cp1, quad, 64) + b1[quad * 4 + 1];
    cv4[2] = __shfl(cp2, quad, 64) + b1[quad * 4 + 2];
    cv4[3] = __shfl(cp3, quad, 64) + b1[quad * 4 + 3];

    // same-wave LDS write -> read: compiler fence (HW DS ops are in-order per wave)
    asm volatile("" ::: "memory");
    __builtin_amdgcn_wave_barrier();

    // ---- A-operand frags (Mt): A[row=h=m16][k=d=quad*8+j] ----
    const int bb0 = m16 * MTS + quad * 8;
    const bf16x8 Bh0 = *(const bf16x8*)&MtHi[w][bb0];
    const bf16x8 Bh1 = *(const bf16x8*)&MtHi[w][bb0 + 32];
    const bf16x8 Bl0 = *(const bf16x8*)&MtLo[w][bb0];
    const bf16x8 Bl1 = *(const bf16x8*)&MtLo[w][bb0 + 32];

    // ---- small operands straight to regs (L2-hot, broadcast) ----
    // lane's 4 W2 rows: h = quad*4 + r
    float4 wa_[4], wb_[4];
    #pragma unroll
    for (int r = 0; r < 4; r++) {
        wa_[r] = *(const float4*)(W2 + (quad * 4 + r) * 8);
        wb_[r] = *(const float4*)(W2 + (quad * 4 + r) * 8 + 4);
    }
    const float4 b2a = *(const float4*)(b2);
    const float4 b2b = *(const float4*)(b2 + 4);
    const float4 w3a = *(const float4*)(W3);
    const float4 w3b = *(const float4*)(W3 + 4);
    const float  b3v = b3[0];

    // fixed softmax shift: |sc| <= 0.125*(|b3| + sum|W3|)  (sigmoid in [0,1])
    const float M = 0.125f * (fabsf(b3v)
                  + fabsf(w3a.x) + fabsf(w3a.y) + fabsf(w3a.z) + fabsf(w3a.w)
                  + fabsf(w3b.x) + fabsf(w3b.y) + fabsf(w3b.z) + fabsf(w3b.w));

    // len==0: reference masks ALL positions -> softmax uniform over 200.
    // Equal scores give the same result, so force sc=0 and keep all 200 valid.
    const int lenEff = (len == 0) ? TT : len;
    const int ntiles = (lenEff + 15) >> 4;

    float ssum = 0.0f;
    float o[16];
    #pragma unroll
    for (int j = 0; j < 16; j++) o[j] = 0.0f;

    // prefetch tile 0: lane holds keys[t = m16][quad*8 .. +7] and [+32 .. +39]
    const float* kp0 = kb + m16 * 64 + quad * 8;
    float4 c0 = *(const float4*)(kp0);
    float4 c1 = *(const float4*)(kp0 + 4);
    float4 c2 = *(const float4*)(kp0 + 32);
    float4 c3 = *(const float4*)(kp0 + 36);

    for (int tile = 0; tile < ntiles; tile++) {
        float4 n0, n1, n2, n3;
        const bool pf = (tile + 1 < ntiles);
        if (pf) {
            int tr = (tile + 1) * 16 + m16;
            if (tr > TT - 1) tr = TT - 1;
            const float* np = kb + tr * 64 + quad * 8;
            n0 = *(const float4*)(np);
            n1 = *(const float4*)(np + 4);
            n2 = *(const float4*)(np + 32);
            n3 = *(const float4*)(np + 36);
        }
        bf16x8 ah0, ah1;
        build_hi(c0, c1, ah0);
        build_hi(c2, c3, ah1);
        // swapped operands: D[h][t] -> lane holds t=m16, h=quad*4+r
        f32x4 acc = {0.f, 0.f, 0.f, 0.f};
        acc = __builtin_amdgcn_mfma_f32_16x16x32_bf16(Bh0, ah0, acc, 0, 0, 0);
        acc = __builtin_amdgcn_mfma_f32_16x16x32_bf16(Bl0, ah0, acc, 0, 0, 0);
        acc = __builtin_amdgcn_mfma_f32_16x16x32_bf16(Bh1, ah1, acc, 0, 0, 0);
        acc = __builtin_amdgcn_mfma_f32_16x16x32_bf16(Bl1, ah1, acc, 0, 0, 0);

        // layer 2 partial over this lane's 4 h's
        float s2[8] = {b2a.x, b2a.y, b2a.z, b2a.w, b2b.x, b2b.y, b2b.z, b2b.w};
        #pragma unroll
        for (int r = 0; r < 4; r++) {
            const float h1 = sigmoidf_(acc[r] + cv4[r]);
            s2[0] = fmaf(h1, wa_[r].x, s2[0]);
            s2[1] = fmaf(h1, wa_[r].y, s2[1]);
            s2[2] = fmaf(h1, wa_[r].z, s2[2]);
            s2[3] = fmaf(h1, wa_[r].w, s2[3]);
            s2[4] = fmaf(h1, wb_[r].x, s2[4]);
            s2[5] = fmaf(h1, wb_[r].y, s2[5]);
            s2[6] = fmaf(h1, wb_[r].z, s2[6]);
            s2[7] = fmaf(h1, wb_[r].w, s2[7]);
        }
        // reduce s2 across quads (same t) -> all lanes hold full s2
        #pragma unroll
        for (int j = 0; j < 8; j++) {
            s2[j] += __shfl_xor(s2[j], 16, 64);
            s2[j] += __shfl_xor(s2[j], 32, 64);
        }
        float s3 = b3v;
        s3 = fmaf(sigmoidf_(s2[0]), w3a.x, s3);
        s3 = fmaf(sigmoidf_(s2[1]), w3a.y, s3);
        s3 = fmaf(sigmoidf_(s2[2]), w3a.z, s3);
        s3 = fmaf(sigmoidf_(s2[3]), w3a.w, s3);
        s3 = fmaf(sigmoidf_(s2[4]), w3b.x, s3);
        s3 = fmaf(sigmoidf_(s2[5]), w3b.y, s3);
        s3 = fmaf(sigmoidf_(s2[6]), w3b.z, s3);
        s3 = fmaf(sigmoidf_(s2[7]), w3b.w, s3);

        const int tg = tile * 16 + m16;
        float sc = (len == 0) ? 0.0f : s3 * 0.125f;   // / sqrt(64)
        if (tg >= lenEff) sc = -1.0e30f;              // masked -> exp underflows to 0
        const float p = __expf(sc - M);               // <= 1 by construction

        ssum += p;
        // per-lane o covers the t == m16 series; cross-t reduce deferred to end
        o[0]  = fmaf(p, c0.x, o[0]);
        o[1]  = fmaf(p, c0.y, o[1]);
        o[2]  = fmaf(p, c0.z, o[2]);
        o[3]  = fmaf(p, c0.w, o[3]);
        o[4]  = fmaf(p, c1.x, o[4]);
        o[5]  = fmaf(p, c1.y, o[5]);
        o[6]  = fmaf(p, c1.z, o[6]);
        o[7]  = fmaf(p, c1.w, o[7]);
        o[8]  = fmaf(p, c2.x, o[8]);
        o[9]  = fmaf(p, c2.y, o[9]);
        o[10] = fmaf(p, c2.z, o[10]);
        o[11] = fmaf(p, c2.w, o[11]);
        o[12] = fmaf(p, c3.x, o[12]);
        o[13] = fmaf(p, c3.y, o[13]);
        o[14] = fmaf(p, c3.z, o[14]);
        o[15] = fmaf(p, c3.w, o[15]);

        if (pf) { c0 = n0; c1 = n1; c2 = n2; c3 = n3; }
    }

    // ---- final cross-t reduction (over m16 lanes) ----
    #pragma unroll
    for (int mask = 1; mask <= 8; mask <<= 1) {
        ssum += __shfl_xor(ssum, mask, 64);
        #pragma unroll
        for (int j = 0; j < 16; j++) o[j] += __shfl_xor(o[j], mask, 64);
    }
    const float inv = 1.0f / ssum;
    if (m16 == 0) {
        #pragma unroll
        for (int j = 0; j < 8; j++) vS[w][quad * 8 + j]      = o[j] * inv;
        #pragma unroll
        for (int j = 0; j < 8; j++) vS[w][32 + quad * 8 + j] = o[8 + j] * inv;
    }
    asm volatile("" ::: "memory");
    __builtin_amdgcn_wave_barrier();

    // ---- out[i=lane] = b4[i] + sum_d v[d] * W4[d][i] (W4 is L2-hot) ----
    float po = b4[lane];
    const float4* vS4 = (const float4*)&vS[w][0];
    #pragma unroll 4
    for (int d0 = 0; d0 < 16; d0++) {
        const float4 vv = vS4[d0];
        const float* w4p = W4 + d0 * 256 + lane;
        po = fmaf(vv.x, w4p[0],   po);
        po = fmaf(vv.y, w4p[64],  po);
        po = fmaf(vv.z, w4p[128], po);
        po = fmaf(vv.w, w4p[192], po);
    }
    out[(size_t)b * 64 + lane] = po;
}

extern "C" void kernel_launch(void* const* d_in, const int* in_sizes, int n_in,
                              void* d_out, int out_size, void* d_ws, size_t ws_size,
                              hipStream_t stream) {
    const float* queries     = (const float*)d_in[0];
    const float* keys        = (const float*)d_in[1];
    const int*   keys_length = (const int*)  d_in[2];
    const float* W1 = (const float*)d_in[3];
    const float* b1 = (const float*)d_in[4];
    const float* W2 = (const float*)d_in[5];
    const float* b2 = (const float*)d_in[6];
    const float* W3 = (const float*)d_in[7];
    const float* b3 = (const float*)d_in[8];
    const float* W4 = (const float*)d_in[9];
    const float* b4 = (const float*)d_in[10];
    float* out = (float*)d_out;

    const int Bn = in_sizes[2];   // 4096
    const int blocks = (Bn + 3) >> 2;   // 4 rows per block (1 wave each)
    din_attn_flash<<<blocks, 256, 0, stream>>>(
        queries, keys, keys_length, W1, b1, W2, b2, W3, b3, W4, b4, out, Bn);
}

// Round 3
// 294.238 us; speedup vs baseline: 1.0701x; 1.0009x over previous
//
#include <hip/hip_runtime.h>
#include <math.h>

// Problem constants: B=4096, T=200, D=64
#define TT 200
#define MTS 72   // Mt row stride in bf16 elems (144 B rows: 16B-aligned)

typedef __attribute__((ext_vector_type(8))) short bf16x8;  // 8 bf16 = 4 VGPRs
typedef __attribute__((ext_vector_type(4))) float f32x4;

union BF8 { bf16x8 v; unsigned u[4]; };

__device__ __forceinline__ float sigmoidf_(float x) {
    return 1.0f / (1.0f + __expf(-x));
}
// packed f32->bf16 RNE convert (1 instr for 2 values)
__device__ __forceinline__ unsigned cvtpk(float a, float b) {
    unsigned r;
    asm("v_cvt_pk_bf16_f32 %0, %1, %2" : "=v"(r) : "v"(a), "v"(b));
    return r;
}
// scalar bf16 RNE (used only in the once-per-wave W1 fold)
__device__ __forceinline__ short f2bf(float x) {
    unsigned u = __float_as_uint(x);
    u += 0x7fff + ((u >> 16) & 1);
    return (short)(u >> 16);
}
__device__ __forceinline__ float bf2f(short s) {
    return __uint_as_float(((unsigned)(unsigned short)s) << 16);
}

// One wave = one batch row; 4 waves (rows) per 256-thread block.
// Single pass over keys, tiles trimmed to ceil(len/16), exact-len predicated
// loads, 2-deep prefetch. Fixed-bound softmax (no online max chain).
// Layer-2 runs as a second MFMA via scrambled-k W2^T fragment. Zero barriers.
__global__ __launch_bounds__(256, 4) void din_attn_flash(
    const float* __restrict__ queries,     // [B,64]
    const float* __restrict__ keys,        // [B,200,64]
    const int*   __restrict__ keys_length, // [B]
    const float* __restrict__ W1,          // [256,16]
    const float* __restrict__ b1,          // [16]
    const float* __restrict__ W2,          // [16,8]
    const float* __restrict__ b2,          // [8]
    const float* __restrict__ W3,          // [8,1]
    const float* __restrict__ b3,          // [1]
    const float* __restrict__ W4,          // [64,64]
    const float* __restrict__ b4,          // [64]
    float* __restrict__ out,               // [B,64]
    int Bn)
{
    __shared__ __align__(16) short MtHi[4][16 * MTS];   // per-wave folded W1^T hi
    __shared__ __align__(16) short MtLo[4][16 * MTS];   // per-wave folded W1^T lo
    __shared__ __align__(16) float vS[4][64];           // per-wave weighted key sum

    const int tid  = threadIdx.x;
    const int w    = tid >> 6;
    const int lane = tid & 63;
    const int m16  = lane & 15;
    const int quad = lane >> 4;

    const int b = blockIdx.x * 4 + w;
    if (b >= Bn) return;
    const int len = __builtin_amdgcn_readfirstlane(keys_length[b]);
    const float* kb = keys + (size_t)b * (TT * 64);

    // ---- fold W1 per wave: lane = (d2 = lane>>2 in 0..15, hg = lane&3) ----
    float cp0 = 0.f, cp1 = 0.f, cp2 = 0.f, cp3 = 0.f;
    {
        const int d2 = lane >> 2;
        const int hg = lane & 3;
        const float4* W1v = (const float4*)W1;   // [256][4] of float4
        #pragma unroll
        for (int dg = 0; dg < 4; dg++) {
            const int d = dg * 16 + d2;
            const float q = queries[b * 64 + d];
            float4 a  = W1v[(0   + d) * 4 + hg];
            float4 bb = W1v[(64  + d) * 4 + hg];
            float4 cc = W1v[(128 + d) * 4 + hg];
            float4 dd = W1v[(192 + d) * 4 + hg];
            float mv0 = bb.x - cc.x + q * dd.x;
            float mv1 = bb.y - cc.y + q * dd.y;
            float mv2 = bb.z - cc.z + q * dd.z;
            float mv3 = bb.w - cc.w + q * dd.w;
            cp0 += q * (a.x + cc.x);
            cp1 += q * (a.y + cc.y);
            cp2 += q * (a.z + cc.z);
            cp3 += q * (a.w + cc.w);
            const int hb = hg * 4;
            short h0 = f2bf(mv0), h1 = f2bf(mv1), h2 = f2bf(mv2), h3 = f2bf(mv3);
            MtHi[w][(hb + 0) * MTS + d] = h0;
            MtHi[w][(hb + 1) * MTS + d] = h1;
            MtHi[w][(hb + 2) * MTS + d] = h2;
            MtHi[w][(hb + 3) * MTS + d] = h3;
            MtLo[w][(hb + 0) * MTS + d] = f2bf(mv0 - bf2f(h0));
            MtLo[w][(hb + 1) * MTS + d] = f2bf(mv1 - bf2f(h1));
            MtLo[w][(hb + 2) * MTS + d] = f2bf(mv2 - bf2f(h2));
            MtLo[w][(hb + 3) * MTS + d] = f2bf(mv3 - bf2f(h3));
        }
        #pragma unroll
        for (int mask = 4; mask <= 32; mask <<= 1) {
            cp0 += __shfl_xor(cp0, mask, 64);
            cp1 += __shfl_xor(cp1, mask, 64);
            cp2 += __shfl_xor(cp2, mask, 64);
            cp3 += __shfl_xor(cp3, mask, 64);
        }
    }
    // cvec for h = quad*4 + r from lane 'quad' (which holds hg == quad)
    float cv4[4];
    cv4[0] = __shfl(cp0, quad, 64) + b1[quad * 4 + 0];
    cv4[1] = __shfl(cp1, quad, 64) + b1[quad * 4 + 1];
    cv4[2] = __shfl(cp2, quad, 64) + b1[quad * 4 + 2];
    cv4[3] = __shfl(cp3, quad, 64) + b1[quad * 4 + 3];

    // same-wave LDS write -> read (HW DS ops in-order per wave)
    asm volatile("" ::: "memory");
    __builtin_amdgcn_wave_barrier();

    // ---- scorer A-frags (Mt): A[row=h=m16][k=d=quad*8+j] ----
    const int bb0 = m16 * MTS + quad * 8;
    const bf16x8 Bh0 = *(const bf16x8*)&MtHi[w][bb0];
    const bf16x8 Bh1 = *(const bf16x8*)&MtHi[w][bb0 + 32];
    const bf16x8 Bl0 = *(const bf16x8*)&MtLo[w][bb0];
    const bf16x8 Bl1 = *(const bf16x8*)&MtLo[w][bb0 + 32];

    // ---- layer-2 A-frag: W2^T in scrambled-k order ----
    // k-slot quad*8+j (j<4) carries h = quad*4+j; slots j>=4 are zero.
    // A[row=m16=k_out][k-slot]: real for k_out<8 only.
    BF8 a2;
    {
        float w2f[4];
        #pragma unroll
        for (int j = 0; j < 4; j++)
            w2f[j] = (m16 < 8) ? W2[(quad * 4 + j) * 8 + m16] : 0.0f;
        a2.u[0] = cvtpk(w2f[0], w2f[1]);
        a2.u[1] = cvtpk(w2f[2], w2f[3]);
        a2.u[2] = 0u;
        a2.u[3] = 0u;
    }

    // ---- tiny operands ----
    const float4 b2a = *(const float4*)(b2);
    const float4 b2b = *(const float4*)(b2 + 4);
    const float4 w3a = *(const float4*)(W3);
    const float4 w3b = *(const float4*)(W3 + 4);
    const float  b3v = b3[0];
    // per-lane layer-3 coefs for k = quad*4 + r (zero for pad quads 2,3)
    const float b2k0 = quad == 0 ? b2a.x : (quad == 1 ? b2b.x : 0.f);
    const float b2k1 = quad == 0 ? b2a.y : (quad == 1 ? b2b.y : 0.f);
    const float b2k2 = quad == 0 ? b2a.z : (quad == 1 ? b2b.z : 0.f);
    const float b2k3 = quad == 0 ? b2a.w : (quad == 1 ? b2b.w : 0.f);
    const float w3k0 = quad == 0 ? w3a.x : (quad == 1 ? w3b.x : 0.f);
    const float w3k1 = quad == 0 ? w3a.y : (quad == 1 ? w3b.y : 0.f);
    const float w3k2 = quad == 0 ? w3a.z : (quad == 1 ? w3b.z : 0.f);
    const float w3k3 = quad == 0 ? w3a.w : (quad == 1 ? w3b.w : 0.f);

    // fixed softmax shift: |sc| <= 0.125*(|b3| + sum|W3|)
    const float M = 0.125f * (fabsf(b3v)
                  + fabsf(w3a.x) + fabsf(w3a.y) + fabsf(w3a.z) + fabsf(w3a.w)
                  + fabsf(w3b.x) + fabsf(w3b.y) + fabsf(w3b.z) + fabsf(w3b.w));

    // len==0: all positions masked in ref -> uniform softmax; sc=0 everywhere.
    const int lenEff = (len == 0) ? TT : len;
    const int ntiles = (lenEff + 15) >> 4;

    float ssum = 0.0f;
    float o[16];
    #pragma unroll
    for (int j = 0; j < 16; j++) o[j] = 0.0f;

    const float4 z4 = {0.f, 0.f, 0.f, 0.f};
    // exact-len predicated tile load: row t = tile*16 + m16
    #define LOADT(TL, A0, A1, A2, A3)                                   \
        { const int t_ = (TL) * 16 + m16;                               \
          if (t_ < lenEff) {                                            \
              const float* p_ = kb + t_ * 64 + quad * 8;                \
              A0 = *(const float4*)(p_);                                \
              A1 = *(const float4*)(p_ + 4);                            \
              A2 = *(const float4*)(p_ + 32);                           \
              A3 = *(const float4*)(p_ + 36);                           \
          } else { A0 = z4; A1 = z4; A2 = z4; A3 = z4; } }

    float4 c0, c1, c2, c3, n0, n1, n2, n3;
    LOADT(0, c0, c1, c2, c3);
    LOADT(1, n0, n1, n2, n3);

    for (int tile = 0; tile < ntiles; tile++) {
        float4 m0, m1, m2, m3;
        LOADT(tile + 2, m0, m1, m2, m3);   // predicate auto-skips past-end tiles

        // keys -> bf16 (packed converts)
        BF8 ah0, ah1;
        ah0.u[0] = cvtpk(c0.x, c0.y);  ah0.u[1] = cvtpk(c0.z, c0.w);
        ah0.u[2] = cvtpk(c1.x, c1.y);  ah0.u[3] = cvtpk(c1.z, c1.w);
        ah1.u[0] = cvtpk(c2.x, c2.y);  ah1.u[1] = cvtpk(c2.z, c2.w);
        ah1.u[2] = cvtpk(c3.x, c3.y);  ah1.u[3] = cvtpk(c3.z, c3.w);

        // layer 1: D[h][t], lane holds t=m16, h=quad*4+r
        f32x4 acc = {0.f, 0.f, 0.f, 0.f};
        acc = __builtin_amdgcn_mfma_f32_16x16x32_bf16(Bh0, ah0.v, acc, 0, 0, 0);
        acc = __builtin_amdgcn_mfma_f32_16x16x32_bf16(Bl0, ah0.v, acc, 0, 0, 0);
        acc = __builtin_amdgcn_mfma_f32_16x16x32_bf16(Bh1, ah1.v, acc, 0, 0, 0);
        acc = __builtin_amdgcn_mfma_f32_16x16x32_bf16(Bl1, ah1.v, acc, 0, 0, 0);

        // sigmoid + pack h1 into scrambled-k B-frag (slots j>=4 zero)
        const float h10 = sigmoidf_(acc[0] + cv4[0]);
        const float h11 = sigmoidf_(acc[1] + cv4[1]);
        const float h12 = sigmoidf_(acc[2] + cv4[2]);
        const float h13 = sigmoidf_(acc[3] + cv4[3]);
        BF8 hb;
        hb.u[0] = cvtpk(h10, h11);
        hb.u[1] = cvtpk(h12, h13);
        hb.u[2] = 0u;
        hb.u[3] = 0u;

        // layer 2: D2[k][t] = sum_h W2T[k][h] h1[h][t]; lane holds k=quad*4+r
        f32x4 acc2 = {0.f, 0.f, 0.f, 0.f};
        acc2 = __builtin_amdgcn_mfma_f32_16x16x32_bf16(a2.v, hb.v, acc2, 0, 0, 0);

        // layer 3 partial over this lane's 4 k's, then cross-quad reduce
        float s3p;
        s3p = sigmoidf_(acc2[0] + b2k0) * w3k0;
        s3p = fmaf(sigmoidf_(acc2[1] + b2k1), w3k1, s3p);
        s3p = fmaf(sigmoidf_(acc2[2] + b2k2), w3k2, s3p);
        s3p = fmaf(sigmoidf_(acc2[3] + b2k3), w3k3, s3p);
        s3p += __shfl_xor(s3p, 16, 64);
        s3p += __shfl_xor(s3p, 32, 64);

        const int tg = tile * 16 + m16;
        float sc = (len == 0) ? 0.0f : (s3p + b3v) * 0.125f;   // / sqrt(64)
        if (tg >= lenEff) sc = -1.0e30f;                        // -> exp == 0
        const float p = __expf(sc - M);                         // <= 1

        ssum += p;
        o[0]  = fmaf(p, c0.x, o[0]);
        o[1]  = fmaf(p, c0.y, o[1]);
        o[2]  = fmaf(p, c0.z, o[2]);
        o[3]  = fmaf(p, c0.w, o[3]);
        o[4]  = fmaf(p, c1.x, o[4]);
        o[5]  = fmaf(p, c1.y, o[5]);
        o[6]  = fmaf(p, c1.z, o[6]);
        o[7]  = fmaf(p, c1.w, o[7]);
        o[8]  = fmaf(p, c2.x, o[8]);
        o[9]  = fmaf(p, c2.y, o[9]);
        o[10] = fmaf(p, c2.z, o[10]);
        o[11] = fmaf(p, c2.w, o[11]);
        o[12] = fmaf(p, c3.x, o[12]);
        o[13] = fmaf(p, c3.y, o[13]);
        o[14] = fmaf(p, c3.z, o[14]);
        o[15] = fmaf(p, c3.w, o[15]);

        c0 = n0; c1 = n1; c2 = n2; c3 = n3;
        n0 = m0; n1 = m1; n2 = m2; n3 = m3;
    }
    #undef LOADT

    // ---- final cross-t reduction (over m16 lanes) ----
    #pragma unroll
    for (int mask = 1; mask <= 8; mask <<= 1) {
        ssum += __shfl_xor(ssum, mask, 64);
        #pragma unroll
        for (int j = 0; j < 16; j++) o[j] += __shfl_xor(o[j], mask, 64);
    }
    const float inv = 1.0f / ssum;
    if (m16 == 0) {
        #pragma unroll
        for (int j = 0; j < 8; j++) vS[w][quad * 8 + j]      = o[j] * inv;
        #pragma unroll
        for (int j = 0; j < 8; j++) vS[w][32 + quad * 8 + j] = o[8 + j] * inv;
    }
    asm volatile("" ::: "memory");
    __builtin_amdgcn_wave_barrier();

    // ---- out[i=lane] = b4[i] + sum_d v[d] * W4[d][i] (W4 is L2-hot) ----
    float po = b4[lane];
    const float4* vS4 = (const float4*)&vS[w][0];
    #pragma unroll 4
    for (int d0 = 0; d0 < 16; d0++) {
        const float4 vv = vS4[d0];
        const float* w4p = W4 + d0 * 256 + lane;
        po = fmaf(vv.x, w4p[0],   po);
        po = fmaf(vv.y, w4p[64],  po);
        po = fmaf(vv.z, w4p[128], po);
        po = fmaf(vv.w, w4p[192], po);
    }
    out[(size_t)b * 64 + lane] = po;
}

extern "C" void kernel_launch(void* const* d_in, const int* in_sizes, int n_in,
                              void* d_out, int out_size, void* d_ws, size_t ws_size,
                              hipStream_t stream) {
    const float* queries     = (const float*)d_in[0];
    const float* keys        = (const float*)d_in[1];
    const int*   keys_length = (const int*)  d_in[2];
    const float* W1 = (const float*)d_in[3];
    const float* b1 = (const float*)d_in[4];
    const float* W2 = (const float*)d_in[5];
    const float* b2 = (const float*)d_in[6];
    const float* W3 = (const float*)d_in[7];
    const float* b3 = (const float*)d_in[8];
    const float* W4 = (const float*)d_in[9];
    const float* b4 = (const float*)d_in[10];
    float* out = (float*)d_out;

    const int Bn = in_sizes[2];   // 4096
    const int blocks = (Bn + 3) >> 2;   // 4 rows per block (1 wave each)
    din_attn_flash<<<blocks, 256, 0, stream>>>(
        queries, keys, keys_length, W1, b1, W2, b2, W3, b3, W4, b4, out, Bn);
}